// Round 7
// baseline (190.841 us; speedup 1.0000x reference)
//
#include <hip/hip_runtime.h>
#include <math.h>

#define B_   8
#define C_   256
#define H_   64
#define W_   64
#define O_   256
#define KK_  9
#define CK_  2304      // C_*KK_
#define HW_  4096      // H_*W_
#define BN_EPS 1e-5f

typedef __bf16 bf16x8 __attribute__((ext_vector_type(8)));
typedef float  f32x4  __attribute__((ext_vector_type(4)));

static __device__ __forceinline__ unsigned short f2bf(float f) {   // RNE (weights)
    unsigned int u = __float_as_uint(f);
    unsigned int r = (u + 0x7fffu + ((u >> 16) & 1u)) >> 16;
    return (unsigned short)r;
}
// pack two f32 -> bf16x2 with round-half-up (1 add per val + 1 v_perm)
static __device__ __forceinline__ unsigned int packbf2(float lo, float hi) {
    unsigned int ul = __float_as_uint(lo) + 0x8000u;
    unsigned int uh = __float_as_uint(hi) + 0x8000u;
    return __builtin_amdgcn_perm(uh, ul, 0x07060302u);
}

// ---- kernel 0: prep = transpose x -> xF (NHWC f32), repack w -> wKf (B-frag
//      order bf16), repack w_off -> wof (frag order bf16, zero-padded to 32)
__global__ __launch_bounds__(256) void prep_kernel(
    const float* __restrict__ x, const float* __restrict__ w,
    const float* __restrict__ w_off,
    float* __restrict__ xF, unsigned short* __restrict__ wKf,
    unsigned short* __restrict__ wof)
{
    int blk = blockIdx.x;
    if (blk < 2048) {
        __shared__ float tile[64][65];
        const int b   = blk & 7;
        const int ct  = (blk >> 3) & 3;
        const int hwt = blk >> 5;
        const int c0  = ct * 64, hw0 = hwt * 64;
        const int tl  = threadIdx.x & 63, tg = threadIdx.x >> 6;
#pragma unroll
        for (int r = 0; r < 16; ++r) {
            int c_l = tg + r * 4;
            tile[c_l][tl] = x[((size_t)(b * C_ + c0 + c_l)) * HW_ + hw0 + tl];
        }
        __syncthreads();
#pragma unroll
        for (int r = 0; r < 16; ++r) {
            int hw_l = tg + r * 4;
            xF[((size_t)(b * HW_ + hw0 + hw_l)) * C_ + c0 + tl] = tile[tl][hw_l];
        }
    } else if (blk < 2048 + 2304) {
        int idx = (blk - 2048) * 256 + threadIdx.x;   // linear over w, coalesced read
        int o   = idx / CK_;
        int rem = idx - o * CK_;
        int c   = rem / 9;
        int tap = rem - c * 9;
        int NT  = o >> 4, n16 = o & 15;
        int kap = tap * 256 + c;
        int KC  = kap >> 5, kr = kap & 31;
        int lane = ((kr >> 3) << 4) | n16, e = kr & 7;
        wKf[((size_t)(NT * 72 + KC) * 64 + lane) * 8 + e] = f2bf(w[idx]);
    } else {
        int idx = (blk - 4352) * 256 + threadIdx.x;   // < 73728, dest-indexed
        int NT  = idx / 36864;
        int r   = idx - NT * 36864;
        int KC  = r >> 9;
        int r2  = r & 511;
        int lane = r2 >> 3, e = r2 & 7;
        int n16 = lane & 15, q = lane >> 4;
        int o   = NT * 16 + n16;
        int kap = KC * 32 + q * 8 + e;
        int tap = kap >> 8, c = kap & 255;
        wof[idx] = (o < 27) ? f2bf(w_off[(o * C_ + c) * KK_ + tap])
                            : (unsigned short)0;
    }
}

// ---- kernel 1: fused offset-conv (MFMA) + sample + MFMA GEMM + BN + ReLU
// grid 512 = (b = blk&7) x (h = blk>>3). 512 thr / 8 waves.
// Phase A: offset conv for this row's 64 px (wave = 16px x 16t tile, K=72).
// Phase B: MFMA wave wv = 64 px x o [wv*32,+32); sampling wave wv = px [wv*8,+8),
//          lane = channel-quad (4 ch, 16 B f32 loads).
__global__ __launch_bounds__(512, 4) void dcn_fused_kernel(
    const float* __restrict__ xF, const unsigned short* __restrict__ wKf,
    const unsigned short* __restrict__ wof, const float* __restrict__ b_off,
    const float* __restrict__ bias, const float* __restrict__ gamma,
    const float* __restrict__ beta, const float* __restrict__ rmean,
    const float* __restrict__ rvar, float* __restrict__ out)
{
    // region 0 (0..34847):      rowbuf [66][264] bf16  (phase A), then
    //                           wgtv[576] float4 (0..9215) + idxv[576] int4 (9216..18431)
    // region 1 (34848..41759):  omb [27][64] f32
    // region 2 (41760..74527):  Abuf [8][4][64][8] bf16
    __shared__ __align__(16) unsigned char smem[74528];
    unsigned short* rowbuf = (unsigned short*)smem;
    float4*         wgtv   = (float4*)smem;
    int4*           idxv   = (int4*)(smem + 9216);
    typedef float OmbT[27][64];
    OmbT& omb = *(OmbT*)(smem + 34848);
    typedef unsigned short AbufT[8][4][64][8];
    AbufT& Abuf = *(AbufT*)(smem + 41760);

    const int blk = blockIdx.x;
    const int b = blk & 7, h = blk >> 3;
    const int tid = threadIdx.x, lane = tid & 63, wv = tid >> 6;
    const int m16 = lane & 15, q = lane >> 4;

    // ================= Phase A: offset conv =================
    // zero halo rows (px=-1 -> row0, px=64 -> row65); visible after first barrier
    if (tid < 33) {
        *(uint4*)&rowbuf[tid * 8] = make_uint4(0u, 0u, 0u, 0u);
    } else if (tid >= 256 && tid < 289) {
        *(uint4*)&rowbuf[65 * 264 + (tid - 256) * 8] = make_uint4(0u, 0u, 0u, 0u);
    }

    const int mi_a = wv & 3, nj_a = wv >> 2;
    f32x4 oacc = {0.f, 0.f, 0.f, 0.f};
    const uint4* wof4 = (const uint4*)wof;

    for (int r = 0; r < 3; ++r) {
        const int hh = h - 1 + r;
        const bool vr = (hh >= 0) && (hh < H_);   // block-uniform
        __syncthreads();                  // prior r's LDS reads complete / halos visible
        if (vr) {
            const float* src = xF + ((size_t)(b * HW_ + hh * W_)) * C_;
#pragma unroll
            for (int i = 0; i < 4; ++i) {
                const int idx8 = i * 512 + tid;           // 2048 chunks of 8 ch
                f32x4 v0 = *(const f32x4*)(src + idx8 * 8);
                f32x4 v1 = *(const f32x4*)(src + idx8 * 8 + 4);
                uint4 pk;
                pk.x = packbf2(v0[0], v0[1]);
                pk.y = packbf2(v0[2], v0[3]);
                pk.z = packbf2(v1[0], v1[1]);
                pk.w = packbf2(v1[2], v1[3]);
                const int px = idx8 >> 5, c8 = (idx8 & 31) * 8;
                *(uint4*)&rowbuf[(px + 1) * 264 + c8] = pk;
            }
        }
        __syncthreads();
        if (vr) {
#pragma unroll
            for (int s = 0; s < 3; ++s) {
                const unsigned short* arow = &rowbuf[(mi_a * 16 + m16 + s) * 264 + q * 8];
#pragma unroll
                for (int cc = 0; cc < 8; ++cc) {
                    bf16x8 a = *(const bf16x8*)&arow[cc * 32];
                    uint4 braw = wof4[(size_t)(nj_a * 72 + (r * 3 + s) * 8 + cc) * 64 + lane];
                    oacc = __builtin_amdgcn_mfma_f32_16x16x32_bf16(
                        a, __builtin_bit_cast(bf16x8, braw), oacc, 0, 0, 0);
                }
            }
        }
    }
    // phase-A epilogue: bias + sigmoid(mod) -> omb[t][px]
    {
        const int t = nj_a * 16 + m16;
        if (t < 27) {
            const float bo = b_off[t];
            float s0 = oacc[0] + bo, s1 = oacc[1] + bo,
                  s2 = oacc[2] + bo, s3 = oacc[3] + bo;
            if (t >= 18) {
                s0 = 1.f / (1.f + expf(-s0));
                s1 = 1.f / (1.f + expf(-s1));
                s2 = 1.f / (1.f + expf(-s2));
                s3 = 1.f / (1.f + expf(-s3));
            }
            float4 rr; rr.x = s0; rr.y = s1; rr.z = s2; rr.w = s3;
            *(float4*)&omb[t][mi_a * 16 + q * 4] = rr;
        }
    }
    __syncthreads();                      // omb visible; rowbuf dead

    // ---- per-(pixel,tap) tables (overwrite rowbuf region) ----
    for (int i = tid; i < 576; i += 512) {
        int p = i / 9, t = i - p * 9;
        float dy = omb[t][p];
        float dx = omb[t + 9][p];
        float md = omb[t + 18][p];
        float py = (float)(h - 1 + t / 3) + dy;
        float px = (float)(p - 1 + t % 3) + dx;
        float y0f = floorf(py), x0f = floorf(px);
        int   y0 = (int)y0f,    x0 = (int)x0f;
        float fy = py - y0f,    fx = px - x0f;
        int y0c = min(max(y0,     0), H_ - 1), y1c = min(max(y0 + 1, 0), H_ - 1);
        int x0c = min(max(x0,     0), W_ - 1), x1c = min(max(x0 + 1, 0), W_ - 1);
        float vy0 = (y0     >= 0 && y0     < H_) ? 1.f : 0.f;
        float vy1 = (y0 + 1 >= 0 && y0 + 1 < H_) ? 1.f : 0.f;
        float vx0 = (x0     >= 0 && x0     < W_) ? 1.f : 0.f;
        float vx1 = (x0 + 1 >= 0 && x0 + 1 < W_) ? 1.f : 0.f;
        wgtv[i] = make_float4((1.f - fy) * (1.f - fx) * vy0 * vx0 * md,
                              (1.f - fy) * fx         * vy0 * vx1 * md,
                              fy         * (1.f - fx) * vy1 * vx0 * md,
                              fy         * fx         * vy1 * vx1 * md);
        const int rowb = (b * HW_) * (C_ * 4);    // byte offset of batch b in xF
        idxv[i] = make_int4(rowb + (y0c * W_ + x0c) * (C_ * 4),
                            rowb + (y0c * W_ + x1c) * (C_ * 4),
                            rowb + (y1c * W_ + x0c) * (C_ * 4),
                            rowb + (y1c * W_ + x1c) * (C_ * 4));
    }
    __syncthreads();

    // ================= Phase B: sample + GEMM =================
    f32x4 acc[4][2];
#pragma unroll
    for (int mi = 0; mi < 4; ++mi)
#pragma unroll
        for (int nj = 0; nj < 2; ++nj)
#pragma unroll
            for (int r = 0; r < 4; ++r) acc[mi][nj][r] = 0.f;

    const uint4* wKf4 = (const uint4*)wKf;
    const char*  xFb  = (const char*)xF;

    // sampling write-dest precompute (lane covers channels 4*lane .. 4*lane+3)
    const int s_cc = lane >> 3;                   // 32-ch chunk
    const int s_q2 = (lane >> 1) & 3;             // k-quad within chunk
    const int s_j0 = (lane & 1) * 4;              // element offset within frag row
    const int s_xr = (s_q2 << 1) ^ s_cc;          // XOR swizzle for bank spread
    const int s_mi = wv >> 1;                     // m-tile this wave's pixels fall in
    const int s_pb = (wv & 1) * 8;                // pixel base within m-tile
    const int loff = lane * 16;                   // byte offset within 1-KiB pixel row

    const int r_row = lane ^ ((lane >> 4) << 1);  // MFMA-side read row (pre-XOR by cc)

    for (int tap = 0; tap < 9; ++tap) {
        // ---- sample 8 pixels: coalesced 1-KiB corner loads, packed-f32 weighted sum
        uint2 pk[8];
#pragma unroll
        for (int pp = 0; pp < 8; ++pp) {
            const int p = wv * 8 + pp;
            const int4   iq = idxv[p * 9 + tap];
            const float4 wq = wgtv[p * 9 + tap];
            f32x4 c0 = *(const f32x4*)(xFb + iq.x + loff);
            f32x4 c1 = *(const f32x4*)(xFb + iq.y + loff);
            f32x4 c2 = *(const f32x4*)(xFb + iq.z + loff);
            f32x4 c3 = *(const f32x4*)(xFb + iq.w + loff);
            f32x4 g = c0 * wq.x + c1 * wq.y + c2 * wq.z + c3 * wq.w;
            pk[pp].x = packbf2(g[0], g[1]);
            pk[pp].y = packbf2(g[2], g[3]);
        }

        __syncthreads();                  // previous tap's A-frag reads complete
#pragma unroll
        for (int pp = 0; pp < 8; ++pp) {
            const int P   = s_pb + pp;                     // pixel & 15
            const int row = (P ^ s_xr) | (s_q2 << 4);      // swizzled frag row
            *(uint2*)&Abuf[s_cc][s_mi][row][s_j0] = pk[pp];
        }
        __syncthreads();                  // tap's A tile visible

        // ---- MFMA: 8 K-steps of 32 channels ----
#pragma unroll
        for (int cc = 0; cc < 8; ++cc) {
            const int KC = tap * 8 + cc;
            const int rr = r_row ^ cc;
            uint4 braw[2];
#pragma unroll
            for (int nj = 0; nj < 2; ++nj)
                braw[nj] = wKf4[(size_t)((wv * 2 + nj) * 72 + KC) * 64 + lane];
            bf16x8 a[4];
#pragma unroll
            for (int mi = 0; mi < 4; ++mi)
                a[mi] = *(const bf16x8*)&Abuf[cc][mi][rr][0];
#pragma unroll
            for (int nj = 0; nj < 2; ++nj) {
                bf16x8 bb = __builtin_bit_cast(bf16x8, braw[nj]);
#pragma unroll
                for (int mi = 0; mi < 4; ++mi)
                    acc[mi][nj] = __builtin_amdgcn_mfma_f32_16x16x32_bf16(
                        a[mi], bb, acc[mi][nj], 0, 0, 0);
            }
        }
    }

    // ---- epilogue: conv bias + BN + ReLU, float4 stores ----
#pragma unroll
    for (int nj = 0; nj < 2; ++nj) {
        const int o = wv * 32 + nj * 16 + (lane & 15);
        const float inv = gamma[o] * rsqrtf(rvar[o] + BN_EPS);
        const float sh  = beta[o] + (bias[o] - rmean[o]) * inv;
        float* ob = out + ((size_t)(b * O_ + o)) * HW_ + h * W_;
#pragma unroll
        for (int mi = 0; mi < 4; ++mi) {
            f32x4 v = acc[mi][nj];
            float4 r;
            r.x = fmaxf(v[0] * inv + sh, 0.f);
            r.y = fmaxf(v[1] * inv + sh, 0.f);
            r.z = fmaxf(v[2] * inv + sh, 0.f);
            r.w = fmaxf(v[3] * inv + sh, 0.f);
            *(float4*)&ob[mi * 16 + (lane >> 4) * 4] = r;
        }
    }
}

extern "C" void kernel_launch(void* const* d_in, const int* in_sizes, int n_in,
                              void* d_out, int out_size, void* d_ws, size_t ws_size,
                              hipStream_t stream) {
    const float* x     = (const float*)d_in[0];
    const float* w_off = (const float*)d_in[1];
    const float* b_off = (const float*)d_in[2];
    const float* w     = (const float*)d_in[3];
    const float* bias  = (const float*)d_in[4];
    const float* gamma = (const float*)d_in[5];
    const float* beta  = (const float*)d_in[6];
    const float* rmean = (const float*)d_in[7];
    const float* rvar  = (const float*)d_in[8];
    float* out = (float*)d_out;

    float*          xF  = (float*)d_ws;                       // 8388608 f32 (32 MB)
    unsigned short* wKf = (unsigned short*)(xF + 8388608);    // 589824 bf16
    unsigned short* wof = wKf + 589824;                       // 73728 bf16

    prep_kernel<<<4640, 256, 0, stream>>>(x, w, w_off, xF, wKf, wof);
    dcn_fused_kernel<<<512, 512, 0, stream>>>(
        xF, wKf, wof, b_off, bias, gamma, beta, rmean, rvar, out);
}

// Round 8
// 183.098 us; speedup vs baseline: 1.0423x; 1.0423x over previous
//
#include <hip/hip_runtime.h>
#include <math.h>

#define B_   8
#define C_   256
#define H_   64
#define W_   64
#define O_   256
#define KK_  9
#define CK_  2304      // C_*KK_
#define HW_  4096      // H_*W_
#define BN_EPS 1e-5f

typedef __bf16 bf16x8 __attribute__((ext_vector_type(8)));
typedef float  f32x4  __attribute__((ext_vector_type(4)));

static __device__ __forceinline__ unsigned short f2bf(float f) {   // RNE (weights)
    unsigned int u = __float_as_uint(f);
    unsigned int r = (u + 0x7fffu + ((u >> 16) & 1u)) >> 16;
    return (unsigned short)r;
}
// pack two f32 -> bf16x2 with round-half-up (2 adds + 1 v_perm)
static __device__ __forceinline__ unsigned int packbf2(float lo, float hi) {
    unsigned int ul = __float_as_uint(lo) + 0x8000u;
    unsigned int uh = __float_as_uint(hi) + 0x8000u;
    return __builtin_amdgcn_perm(uh, ul, 0x07060302u);
}
static __device__ __forceinline__ float bflo(unsigned int u) {
    return __uint_as_float(u << 16);
}
static __device__ __forceinline__ float bfhi(unsigned int u) {
    return __uint_as_float(u & 0xffff0000u);
}

// ---- kernel 0: prep. 656 blocks x 256 thr.
//  blk <512      : transpose x[b][c][hw] f32 -> xT[b][hw][c] bf16 (one (b,h) row-block)
//  blk 512..639  : repack w -> wKf  (B-frag order, LDS-staged, coalesced both sides)
//  blk 640..655  : repack w_off -> wof (same, o>=27 zero-padded)
__global__ __launch_bounds__(256) void prep_kernel(
    const float* __restrict__ x, const float* __restrict__ w,
    const float* __restrict__ w_off,
    unsigned short* __restrict__ xT, unsigned short* __restrict__ wKf,
    unsigned short* __restrict__ wof)
{
    __shared__ float tile[64][65];     // transpose staging
    __shared__ float wbuf[4608];       // weight staging (16 o x 288)

    const int blk = blockIdx.x;
    const int tid = threadIdx.x, lane = tid & 63, tg = tid >> 6;

    if (blk < 512) {
        const int b = blk & 7, h = blk >> 3;
        const int hwb = h * W_;
#pragma unroll
        for (int ct = 0; ct < 4; ++ct) {
            const int c0 = ct * 64;
            // stage 64c x 64hw tile (coalesced dword reads, conflict-free LDS)
#pragma unroll
            for (int r = 0; r < 16; ++r) {
                int c_l = tg + r * 4;
                tile[c_l][lane] = x[((size_t)(b * C_ + c0 + c_l)) * HW_ + hwb + lane];
            }
            __syncthreads();
            // write: 4 hw rows per instr, 4 ch per lane packed -> uint2 (8B/lane)
#pragma unroll
            for (int it = 0; it < 4; ++it) {
                const int hw_l = tg * 16 + it * 4 + (lane >> 4);
                const int c_l4 = (lane & 15) * 4;
                float v0 = tile[c_l4 + 0][hw_l];
                float v1 = tile[c_l4 + 1][hw_l];
                float v2 = tile[c_l4 + 2][hw_l];
                float v3 = tile[c_l4 + 3][hw_l];
                uint2 pk;
                pk.x = packbf2(v0, v1);
                pk.y = packbf2(v2, v3);
                *(uint2*)&xT[((size_t)(b * HW_ + hwb + hw_l)) * C_ + c0 + c_l4] = pk;
            }
            __syncthreads();
        }
    } else if (blk < 640) {
        const int t2 = blk - 512;
        const int NT = t2 >> 3, cb = t2 & 7;
        // stage w[NT*16..+16][cb*32..+32][0..9) = 16 x 288 contiguous floats per o
#pragma unroll
        for (int i = 0; i < 18; ++i) {
            int j = i * 256 + tid;
            int o_l = j / 288, rest = j - o_l * 288;
            wbuf[o_l * 288 + rest] = w[(size_t)(NT * 16 + o_l) * CK_ + cb * 288 + rest];
        }
        __syncthreads();
        // write dest-linear: 9 taps x 512 contiguous bf16 elems
#pragma unroll
        for (int i = 0; i < 18; ++i) {
            int d = i * 256 + tid;
            int tap = d >> 9, r5 = d & 511;
            int ln = r5 >> 3, e = r5 & 7;
            int n16 = ln & 15, q = ln >> 4;
            float val = wbuf[n16 * 288 + (q * 8 + e) * 9 + tap];
            wKf[((size_t)(NT * 72 + tap * 8 + cb) * 64 + ln) * 8 + e] = f2bf(val);
        }
    } else {
        const int t2 = blk - 640;
        const int NT = t2 >> 3, cb = t2 & 7;
#pragma unroll
        for (int i = 0; i < 18; ++i) {
            int j = i * 256 + tid;
            int o_l = j / 288, rest = j - o_l * 288;
            int o = NT * 16 + o_l;
            wbuf[o_l * 288 + rest] =
                (o < 27) ? w_off[(size_t)o * CK_ + cb * 288 + rest] : 0.f;
        }
        __syncthreads();
#pragma unroll
        for (int i = 0; i < 18; ++i) {
            int d = i * 256 + tid;
            int tap = d >> 9, r5 = d & 511;
            int ln = r5 >> 3, e = r5 & 7;
            int n16 = ln & 15, q = ln >> 4;
            float val = wbuf[n16 * 288 + (q * 8 + e) * 9 + tap];
            wof[((size_t)(NT * 72 + tap * 8 + cb) * 64 + ln) * 8 + e] = f2bf(val);
        }
    }
}

// ---- kernel 1: fused offset-conv (MFMA) + sample + MFMA GEMM + BN + ReLU
// grid 512 = (b = blk&7) x (h = blk>>3). 512 thr / 8 waves.
__global__ __launch_bounds__(512, 4) void dcn_fused_kernel(
    const unsigned short* __restrict__ xT, const unsigned short* __restrict__ wKf,
    const unsigned short* __restrict__ wof, const float* __restrict__ b_off,
    const float* __restrict__ bias, const float* __restrict__ gamma,
    const float* __restrict__ beta, const float* __restrict__ rmean,
    const float* __restrict__ rvar, float* __restrict__ out)
{
    // region 0 (0..34847):      rowbuf [66][264] bf16 (phase A), then
    //                           wgtv[576] float4 (0..9215) + idxv[576] int4 (9216..18431)
    // region 1 (34848..41759):  omb [27][64] f32
    // region 2 (41760..74527):  Abuf [8][4][64][8] bf16
    __shared__ __align__(16) unsigned char smem[74528];
    unsigned short* rowbuf = (unsigned short*)smem;
    float4*         wgtv   = (float4*)smem;
    int4*           idxv   = (int4*)(smem + 9216);
    typedef float OmbT[27][64];
    OmbT& omb = *(OmbT*)(smem + 34848);
    typedef unsigned short AbufT[8][4][64][8];
    AbufT& Abuf = *(AbufT*)(smem + 41760);

    const int blk = blockIdx.x;
    const int b = blk & 7, h = blk >> 3;
    const int tid = threadIdx.x, lane = tid & 63, wv = tid >> 6;
    const int m16 = lane & 15, q = lane >> 4;

    // ================= Phase A: offset conv =================
    if (tid < 33) {                                  // zero halo px=-1 (row 0)
        *(uint4*)&rowbuf[tid * 8] = make_uint4(0u, 0u, 0u, 0u);
    } else if (tid >= 256 && tid < 289) {            // zero halo px=64 (row 65)
        *(uint4*)&rowbuf[65 * 264 + (tid - 256) * 8] = make_uint4(0u, 0u, 0u, 0u);
    }

    const int mi_a = wv & 3, nj_a = wv >> 2;
    f32x4 oacc = {0.f, 0.f, 0.f, 0.f};
    const uint4* wof4 = (const uint4*)wof;

    for (int r = 0; r < 3; ++r) {
        const int hh = h - 1 + r;
        const bool vr = (hh >= 0) && (hh < H_);      // block-uniform
        __syncthreads();                             // prior r reads done / halos visible
        if (vr) {
            const uint4* src = (const uint4*)&xT[((size_t)(b * HW_ + hh * W_)) * C_];
#pragma unroll
            for (int i = 0; i < 4; ++i) {
                const int idx8 = i * 512 + tid;      // 2048 chunks of 8 ch (16 B)
                uint4 v = src[idx8];
                const int px = idx8 >> 5, c8 = (idx8 & 31) * 8;
                *(uint4*)&rowbuf[(px + 1) * 264 + c8] = v;
            }
        }
        __syncthreads();
        if (vr) {
#pragma unroll
            for (int s = 0; s < 3; ++s) {
                const unsigned short* arow = &rowbuf[(mi_a * 16 + m16 + s) * 264 + q * 8];
#pragma unroll
                for (int cc = 0; cc < 8; ++cc) {
                    bf16x8 a = *(const bf16x8*)&arow[cc * 32];
                    uint4 braw = wof4[(size_t)(nj_a * 72 + (r * 3 + s) * 8 + cc) * 64 + lane];
                    oacc = __builtin_amdgcn_mfma_f32_16x16x32_bf16(
                        a, __builtin_bit_cast(bf16x8, braw), oacc, 0, 0, 0);
                }
            }
        }
    }
    // phase-A epilogue: bias + sigmoid(mod) -> omb[t][px]
    {
        const int t = nj_a * 16 + m16;
        if (t < 27) {
            const float bo = b_off[t];
            float s0 = oacc[0] + bo, s1 = oacc[1] + bo,
                  s2 = oacc[2] + bo, s3 = oacc[3] + bo;
            if (t >= 18) {
                s0 = 1.f / (1.f + expf(-s0));
                s1 = 1.f / (1.f + expf(-s1));
                s2 = 1.f / (1.f + expf(-s2));
                s3 = 1.f / (1.f + expf(-s3));
            }
            float4 rr; rr.x = s0; rr.y = s1; rr.z = s2; rr.w = s3;
            *(float4*)&omb[t][mi_a * 16 + q * 4] = rr;
        }
    }
    __syncthreads();                      // omb visible; rowbuf dead

    // ---- per-(pixel,tap) tables (overwrite rowbuf region) ----
    for (int i = tid; i < 576; i += 512) {
        int p = i / 9, t = i - p * 9;
        float dy = omb[t][p];
        float dx = omb[t + 9][p];
        float md = omb[t + 18][p];
        float py = (float)(h - 1 + t / 3) + dy;
        float px = (float)(p - 1 + t % 3) + dx;
        float y0f = floorf(py), x0f = floorf(px);
        int   y0 = (int)y0f,    x0 = (int)x0f;
        float fy = py - y0f,    fx = px - x0f;
        int y0c = min(max(y0,     0), H_ - 1), y1c = min(max(y0 + 1, 0), H_ - 1);
        int x0c = min(max(x0,     0), W_ - 1), x1c = min(max(x0 + 1, 0), W_ - 1);
        float vy0 = (y0     >= 0 && y0     < H_) ? 1.f : 0.f;
        float vy1 = (y0 + 1 >= 0 && y0 + 1 < H_) ? 1.f : 0.f;
        float vx0 = (x0     >= 0 && x0     < W_) ? 1.f : 0.f;
        float vx1 = (x0 + 1 >= 0 && x0 + 1 < W_) ? 1.f : 0.f;
        wgtv[i] = make_float4((1.f - fy) * (1.f - fx) * vy0 * vx0 * md,
                              (1.f - fy) * fx         * vy0 * vx1 * md,
                              fy         * (1.f - fx) * vy1 * vx0 * md,
                              fy         * fx         * vy1 * vx1 * md);
        const int rowb = (b * HW_) * (C_ * 2);       // byte offset of batch b in xT
        idxv[i] = make_int4(rowb + (y0c * W_ + x0c) * (C_ * 2),
                            rowb + (y0c * W_ + x1c) * (C_ * 2),
                            rowb + (y1c * W_ + x0c) * (C_ * 2),
                            rowb + (y1c * W_ + x1c) * (C_ * 2));
    }
    __syncthreads();

    // ================= Phase B: sample + GEMM =================
    f32x4 acc[4][2];
#pragma unroll
    for (int mi = 0; mi < 4; ++mi)
#pragma unroll
        for (int nj = 0; nj < 2; ++nj)
#pragma unroll
            for (int r = 0; r < 4; ++r) acc[mi][nj][r] = 0.f;

    const uint4* wKf4 = (const uint4*)wKf;
    const char*  xTb  = (const char*)xT;

    // sampling write-dest precompute (lane covers channels 4*lane .. 4*lane+3)
    const int s_cc = lane >> 3;                   // 32-ch chunk
    const int s_q2 = (lane >> 1) & 3;             // k-quad within chunk
    const int s_j0 = (lane & 1) * 4;              // element offset within frag row
    const int s_xr = (s_q2 << 1) ^ s_cc;          // XOR swizzle for bank spread
    const int s_mi = wv >> 1;                     // m-tile this wave's pixels fall in
    const int s_pb = (wv & 1) * 8;                // pixel base within m-tile
    const int loff = lane * 8;                    // byte offset within 512-B pixel row

    const int r_row = lane ^ ((lane >> 4) << 1);  // MFMA-side read row (pre-XOR by cc)

    for (int tap = 0; tap < 9; ++tap) {
        // ---- sample 8 pixels: coalesced 512-B corner loads, weighted sum ----
        uint2 pk[8];
#pragma unroll
        for (int pp = 0; pp < 8; ++pp) {
            const int p = wv * 8 + pp;
            const int4   iq = idxv[p * 9 + tap];
            const float4 wq = wgtv[p * 9 + tap];
            const uint2 k0 = *(const uint2*)(xTb + iq.x + loff);
            const uint2 k1 = *(const uint2*)(xTb + iq.y + loff);
            const uint2 k2 = *(const uint2*)(xTb + iq.z + loff);
            const uint2 k3 = *(const uint2*)(xTb + iq.w + loff);
            float g0 = wq.x*bflo(k0.x) + wq.y*bflo(k1.x) + wq.z*bflo(k2.x) + wq.w*bflo(k3.x);
            float g1 = wq.x*bfhi(k0.x) + wq.y*bfhi(k1.x) + wq.z*bfhi(k2.x) + wq.w*bfhi(k3.x);
            float g2 = wq.x*bflo(k0.y) + wq.y*bflo(k1.y) + wq.z*bflo(k2.y) + wq.w*bflo(k3.y);
            float g3 = wq.x*bfhi(k0.y) + wq.y*bfhi(k1.y) + wq.z*bfhi(k2.y) + wq.w*bfhi(k3.y);
            pk[pp].x = packbf2(g0, g1);
            pk[pp].y = packbf2(g2, g3);
        }

        __syncthreads();                  // previous tap's A-frag reads complete
#pragma unroll
        for (int pp = 0; pp < 8; ++pp) {
            const int P   = s_pb + pp;                     // pixel & 15
            const int row = (P ^ s_xr) | (s_q2 << 4);      // swizzled frag row
            *(uint2*)&Abuf[s_cc][s_mi][row][s_j0] = pk[pp];
        }
        __syncthreads();                  // tap's A tile visible

        // ---- MFMA: 8 K-steps of 32 channels ----
#pragma unroll
        for (int cc = 0; cc < 8; ++cc) {
            const int KC = tap * 8 + cc;
            const int rr = r_row ^ cc;
            uint4 braw[2];
#pragma unroll
            for (int nj = 0; nj < 2; ++nj)
                braw[nj] = wKf4[(size_t)((wv * 2 + nj) * 72 + KC) * 64 + lane];
            bf16x8 a[4];
#pragma unroll
            for (int mi = 0; mi < 4; ++mi)
                a[mi] = *(const bf16x8*)&Abuf[cc][mi][rr][0];
#pragma unroll
            for (int nj = 0; nj < 2; ++nj) {
                bf16x8 bb = __builtin_bit_cast(bf16x8, braw[nj]);
#pragma unroll
                for (int mi = 0; mi < 4; ++mi)
                    acc[mi][nj] = __builtin_amdgcn_mfma_f32_16x16x32_bf16(
                        a[mi], bb, acc[mi][nj], 0, 0, 0);
            }
        }
    }

    // ---- epilogue: conv bias + BN + ReLU, float4 stores ----
#pragma unroll
    for (int nj = 0; nj < 2; ++nj) {
        const int o = wv * 32 + nj * 16 + (lane & 15);
        const float inv = gamma[o] * rsqrtf(rvar[o] + BN_EPS);
        const float sh  = beta[o] + (bias[o] - rmean[o]) * inv;
        float* ob = out + ((size_t)(b * O_ + o)) * HW_ + h * W_;
#pragma unroll
        for (int mi = 0; mi < 4; ++mi) {
            f32x4 v = acc[mi][nj];
            float4 r;
            r.x = fmaxf(v[0] * inv + sh, 0.f);
            r.y = fmaxf(v[1] * inv + sh, 0.f);
            r.z = fmaxf(v[2] * inv + sh, 0.f);
            r.w = fmaxf(v[3] * inv + sh, 0.f);
            *(float4*)&ob[mi * 16 + (lane >> 4) * 4] = r;
        }
    }
}

extern "C" void kernel_launch(void* const* d_in, const int* in_sizes, int n_in,
                              void* d_out, int out_size, void* d_ws, size_t ws_size,
                              hipStream_t stream) {
    const float* x     = (const float*)d_in[0];
    const float* w_off = (const float*)d_in[1];
    const float* b_off = (const float*)d_in[2];
    const float* w     = (const float*)d_in[3];
    const float* bias  = (const float*)d_in[4];
    const float* gamma = (const float*)d_in[5];
    const float* beta  = (const float*)d_in[6];
    const float* rmean = (const float*)d_in[7];
    const float* rvar  = (const float*)d_in[8];
    float* out = (float*)d_out;

    unsigned short* xT  = (unsigned short*)d_ws;              // 8388608 bf16 (16 MB)
    unsigned short* wKf = xT + 8388608;                       // 589824 bf16
    unsigned short* wof = wKf + 589824;                       // 73728 bf16

    prep_kernel<<<656, 256, 0, stream>>>(x, w, w_off, xT, wKf, wof);
    dcn_fused_kernel<<<512, 512, 0, stream>>>(
        xT, wKf, wof, b_off, bias, gamma, beta, rmean, rvar, out);
}